// Round 1
// baseline (284.063 us; speedup 1.0000x reference)
//
#include <hip/hip_runtime.h>
#include <stdint.h>

// Problem: out = dequant( int8(lhs*ls) @ int8(rhs*rs) ) / (ls*rs)
//   lhs: [4096,4096] fp32, rhs: [4096,4096] fp32, out: [4096,4096] fp32
//   ls = 127 / max(amax(|lhs|), 1e-12), same for rs. Round = RNE (jnp.round).
//
// Workspace layout (needs 32 MiB + 8 B):
//   [0, 16Mi)          qA   int8 [4096][4096] (row-major, M x K)
//   [16Mi, 32Mi)       qBT  int8 [4096][4096] (B transposed: N x K)
//   [32Mi, 32Mi+8)     amax bits: [0]=lhs, [1]=rhs (uint32 fp32 bit patterns)

#define NROW 4096
#define NELEM (4096 * 4096)

typedef __attribute__((ext_vector_type(4))) int int32x4;
typedef const __attribute__((address_space(1))) int8_t* gptr1_t;
typedef __attribute__((address_space(3))) int8_t* lptr3_t;

__global__ void init_amax_kernel(unsigned* amax) {
    if (threadIdx.x < 2) amax[threadIdx.x] = 0u;
}

__global__ void absmax_kernel(const float* __restrict__ x,
                              unsigned* __restrict__ amax_out) {
    __shared__ float red[4];
    const int tid = blockIdx.x * blockDim.x + threadIdx.x;
    const int stride = gridDim.x * blockDim.x;
    const float4* x4 = (const float4*)x;
    float m = 0.0f;
    for (int i = tid; i < NELEM / 4; i += stride) {
        float4 v = x4[i];
        m = fmaxf(m, fmaxf(fmaxf(fabsf(v.x), fabsf(v.y)),
                           fmaxf(fabsf(v.z), fabsf(v.w))));
    }
    // wave-64 reduce
    for (int off = 32; off > 0; off >>= 1)
        m = fmaxf(m, __shfl_down(m, off, 64));
    const int lane = threadIdx.x & 63, wave = threadIdx.x >> 6;
    if (lane == 0) red[wave] = m;
    __syncthreads();
    if (threadIdx.x == 0) {
        float b = fmaxf(fmaxf(red[0], red[1]), fmaxf(red[2], red[3]));
        // |x| >= 0 so fp32 bit pattern is monotone as unsigned
        atomicMax(amax_out, __float_as_uint(b));
    }
}

__device__ __forceinline__ int q8(float v, float s) {
    int r = __float2int_rn(v * s);  // RNE, matches jnp.round
    r = r < -127 ? -127 : r;
    r = r > 127 ? 127 : r;
    return r;
}

// Straight quantize of A (row-major M x K), 1 float4 -> 1 packed dword per thread.
__global__ void quantA_kernel(const float* __restrict__ x,
                              int8_t* __restrict__ q,
                              const unsigned* __restrict__ amax) {
    const float s = 127.0f / fmaxf(__uint_as_float(amax[0]), 1e-12f);
    const int i = blockIdx.x * blockDim.x + threadIdx.x;  // float4 index
    float4 v = ((const float4*)x)[i];
    int b0 = q8(v.x, s), b1 = q8(v.y, s), b2 = q8(v.z, s), b3 = q8(v.w, s);
    int packed = (b0 & 0xff) | ((b1 & 0xff) << 8) | ((b2 & 0xff) << 16)
               | ((b3 & 0xff) << 24);
    ((int*)q)[i] = packed;
}

// Quantize + transpose B (K x N row-major) into qBT (N x K row-major).
// 64x64 tile through LDS; reads coalesced float4 along N, writes int4 along K.
__global__ void quantBT_kernel(const float* __restrict__ B,
                               int8_t* __restrict__ qT,
                               const unsigned* __restrict__ amax) {
    __shared__ int8_t sm[64][68];  // [n_local][k_local], +4 pad
    const float s = 127.0f / fmaxf(__uint_as_float(amax[1]), 1e-12f);
    const int k0 = blockIdx.y * 64, n0 = blockIdx.x * 64;
    const int rl = threadIdx.x >> 4;   // 0..15 (k row within 16-row slab)
    const int nq = threadIdx.x & 15;   // 0..15 (float4 column)
    for (int r = 0; r < 4; ++r) {
        const int kl = r * 16 + rl;
        float4 v = *(const float4*)(B + (size_t)(k0 + kl) * NROW + n0 + nq * 4);
        sm[nq * 4 + 0][kl] = (int8_t)q8(v.x, s);
        sm[nq * 4 + 1][kl] = (int8_t)q8(v.y, s);
        sm[nq * 4 + 2][kl] = (int8_t)q8(v.z, s);
        sm[nq * 4 + 3][kl] = (int8_t)q8(v.w, s);
    }
    __syncthreads();
    const int nl = threadIdx.x >> 2;   // 0..63
    const int kq = threadIdx.x & 3;    // 0..3 (16-byte chunk along K)
    int4 w;
    w.x = *(const int*)&sm[nl][kq * 16 + 0];
    w.y = *(const int*)&sm[nl][kq * 16 + 4];
    w.z = *(const int*)&sm[nl][kq * 16 + 8];
    w.w = *(const int*)&sm[nl][kq * 16 + 12];
    *(int4*)(qT + (size_t)(n0 + nl) * NROW + k0 + kq * 16) = w;
}

// 128x128 tile int8 GEMM, BK=64, mfma_i32_16x16x64_i8, global_load_lds staging.
// LDS chunk layout swizzle: chunk (row, cq) holds global K-quad
// gq = (cq - (row>>1)) & 3, so fragment ds_read_b128s are 2-way-bank (free)
// instead of 8-way, while global_load_lds lane-contiguity is preserved
// (swizzle applied on the global-address side only).
__global__ __launch_bounds__(256) void gemm_i8_kernel(
    const int8_t* __restrict__ qA, const int8_t* __restrict__ qBT,
    float* __restrict__ out, const unsigned* __restrict__ amax) {
    __shared__ int8_t sA[128 * 64];
    __shared__ int8_t sB[128 * 64];

    const int tid = threadIdx.x;
    const int lane = tid & 63;
    const int wave = tid >> 6;
    const int m0 = blockIdx.y * 128, n0 = blockIdx.x * 128;
    const int wm = (wave & 1) * 64;   // wave's 64-row sub-tile
    const int wn = (wave >> 1) * 64;  // wave's 64-col sub-tile

    int32x4 acc[4][4];
#pragma unroll
    for (int mi = 0; mi < 4; ++mi)
#pragma unroll
        for (int ni = 0; ni < 4; ++ni) acc[mi][ni] = (int32x4)(0);

    // staging chunk indices (2 chunks of 16B per tensor per thread)
    const int c0 = tid, c1 = 256 + tid;
    const int row0 = c0 >> 2, cq0 = c0 & 3, gq0 = (cq0 - (row0 >> 1)) & 3;
    const int row1 = c1 >> 2, cq1 = c1 & 3, gq1 = (cq1 - (row1 >> 1)) & 3;

    const int q = lane >> 4;   // K-quad (16 bytes each)
    const int r = lane & 15;   // row (A) / col (B) within 16

    for (int kt = 0; kt < 64; ++kt) {
        const int kb = kt * 64;
        __syncthreads();
        __builtin_amdgcn_global_load_lds(
            (gptr1_t)(qA + (size_t)(m0 + row0) * NROW + kb + gq0 * 16),
            (lptr3_t)(sA + c0 * 16), 16, 0, 0);
        __builtin_amdgcn_global_load_lds(
            (gptr1_t)(qA + (size_t)(m0 + row1) * NROW + kb + gq1 * 16),
            (lptr3_t)(sA + c1 * 16), 16, 0, 0);
        __builtin_amdgcn_global_load_lds(
            (gptr1_t)(qBT + (size_t)(n0 + row0) * NROW + kb + gq0 * 16),
            (lptr3_t)(sB + c0 * 16), 16, 0, 0);
        __builtin_amdgcn_global_load_lds(
            (gptr1_t)(qBT + (size_t)(n0 + row1) * NROW + kb + gq1 * 16),
            (lptr3_t)(sB + c1 * 16), 16, 0, 0);
        __syncthreads();

        int32x4 afrag[4], bfrag[4];
#pragma unroll
        for (int mi = 0; mi < 4; ++mi) {
            const int row = wm + mi * 16 + r;
            afrag[mi] =
                *(const int32x4*)(sA + row * 64 + (((q + (row >> 1)) & 3) * 16));
        }
#pragma unroll
        for (int ni = 0; ni < 4; ++ni) {
            const int row = wn + ni * 16 + r;
            bfrag[ni] =
                *(const int32x4*)(sB + row * 64 + (((q + (row >> 1)) & 3) * 16));
        }
#pragma unroll
        for (int mi = 0; mi < 4; ++mi)
#pragma unroll
            for (int ni = 0; ni < 4; ++ni)
                acc[mi][ni] = __builtin_amdgcn_mfma_i32_16x16x64_i8(
                    afrag[mi], bfrag[ni], acc[mi][ni], 0, 0, 0);
    }

    // epilogue: dequant + store. C/D layout: col = lane&15, row = (lane>>4)*4+reg
    const float ls = 127.0f / fmaxf(__uint_as_float(amax[0]), 1e-12f);
    const float rs = 127.0f / fmaxf(__uint_as_float(amax[1]), 1e-12f);
    const float inv = 1.0f / (ls * rs);
#pragma unroll
    for (int mi = 0; mi < 4; ++mi)
#pragma unroll
        for (int ni = 0; ni < 4; ++ni)
#pragma unroll
            for (int reg = 0; reg < 4; ++reg) {
                const int row = m0 + wm + mi * 16 + q * 4 + reg;
                const int col = n0 + wn + ni * 16 + r;
                out[(size_t)row * NROW + col] = (float)acc[mi][ni][reg] * inv;
            }
}

extern "C" void kernel_launch(void* const* d_in, const int* in_sizes, int n_in,
                              void* d_out, int out_size, void* d_ws,
                              size_t ws_size, hipStream_t stream) {
    const float* lhs = (const float*)d_in[0];
    const float* rhs = (const float*)d_in[1];
    float* out = (float*)d_out;

    int8_t* qA = (int8_t*)d_ws;
    int8_t* qBT = qA + (size_t)16 * 1024 * 1024;
    unsigned* amax = (unsigned*)(qBT + (size_t)16 * 1024 * 1024);

    init_amax_kernel<<<1, 64, 0, stream>>>(amax);
    absmax_kernel<<<256, 256, 0, stream>>>(lhs, amax + 0);
    absmax_kernel<<<256, 256, 0, stream>>>(rhs, amax + 1);
    quantA_kernel<<<NELEM / 4 / 256, 256, 0, stream>>>(lhs, qA, amax);
    quantBT_kernel<<<dim3(64, 64), 256, 0, stream>>>(rhs, qBT, amax);
    gemm_i8_kernel<<<dim3(32, 32), 256, 0, stream>>>(qA, qBT, out, amax);
}